// Round 8
// baseline (1193.755 us; speedup 1.0000x reference)
//
#include <hip/hip_runtime.h>

#define NC    64      // channels C
#define NATTR 10      // node attrs
#define NH    64      // radial MLP hidden
#define NRAD  8       // radial features
#define TEB   128     // CSR positions per edge block
#define MPN   704     // f32 message floats per node

__device__ __forceinline__ float silu_f(float x) { return x / (1.0f + __expf(-x)); }

// ---------------- f16x2 pack helpers + hardware dot2 ----------------------
typedef __fp16 h2v __attribute__((ext_vector_type(2)));

__device__ __forceinline__ unsigned int pkh(float lo, float hi)
{
    union { h2v h; unsigned int u; } cv;
    cv.h = __builtin_amdgcn_cvt_pkrtz(lo, hi);   // v_cvt_pkrtz_f16_f32
    return cv.u;
}
__device__ __forceinline__ h2v uph(unsigned int u)
{
    union { unsigned int u; h2v h; } cv;
    cv.u = u;
    return cv.h;
}

#if defined(__has_builtin)
#if __has_builtin(__builtin_amdgcn_fdot2)
#define HAS_FDOT2 1
#endif
#endif

__device__ __forceinline__ float fd2(unsigned int a, unsigned int b, float c)
{
#ifdef HAS_FDOT2
    return __builtin_amdgcn_fdot2(uph(a), uph(b), c, false);  // v_dot2_f32_f16
#else
    h2v x = uph(a), y = uph(b);
    return c + (float)x[0] * (float)y[0] + (float)x[1] * (float)y[1];
#endif
}

// dual / triple dot of one packed-f16 h row (32 uints = 64 values) against
// register-resident W column slices. One LDS uint4 sweep feeds all dots.
__device__ __forceinline__ void dot2w(const uint4* hp,
    const unsigned int (&Wa)[32], const unsigned int (&Wb)[32],
    float& ra, float& rb)
{
    float a = 0.f, b = 0.f;
    #pragma unroll
    for (int q8 = 0; q8 < 8; q8++) {
        uint4 hu = hp[q8];
        unsigned int hw[4] = {hu.x, hu.y, hu.z, hu.w};
        #pragma unroll
        for (int k = 0; k < 4; k++) {
            a = fd2(hw[k], Wa[q8 * 4 + k], a);
            b = fd2(hw[k], Wb[q8 * 4 + k], b);
        }
    }
    ra = a * 0.125f; rb = b * 0.125f;   // 1/sqrt(64)
}

__device__ __forceinline__ void dot3w(const uint4* hp,
    const unsigned int (&Wa)[32], const unsigned int (&Wb)[32],
    const unsigned int (&Wc)[32],
    float& ra, float& rb, float& rc)
{
    float a = 0.f, b = 0.f, c = 0.f;
    #pragma unroll
    for (int q8 = 0; q8 < 8; q8++) {
        uint4 hu = hp[q8];
        unsigned int hw[4] = {hu.x, hu.y, hu.z, hu.w};
        #pragma unroll
        for (int k = 0; k < 4; k++) {
            a = fd2(hw[k], Wa[q8 * 4 + k], a);
            b = fd2(hw[k], Wb[q8 * 4 + k], b);
            c = fd2(hw[k], Wc[q8 * 4 + k], c);
        }
    }
    ra = a * 0.125f; rb = b * 0.125f; rc = c * 0.125f;
}

// ---------------------------------------------------------------------------
// d_out layout (f32, out_size = N*512):
//   out_s : [0,      N*64 )   -- also CSR int scratch until out written
//   out_v : [N*64,   N*256)
//   sc_s  : [N*256,  N*320)   -- self-linear s scratch until post_kernel
//   sc_v  : [N*320,  N*512)   -- self-linear v scratch until post_kernel
// ws: m[N*704] f32 message accumulator (140.8 MB)
// ---------------------------------------------------------------------------

// ---------------- CSR build (scratch ints live in d_out's out region) ------
__global__ void hist_kernel(const int* __restrict__ rcv, int* __restrict__ deg, int E)
{
    int e = blockIdx.x * 256 + threadIdx.x;
    if (e < E) atomicAdd(&deg[rcv[e]], 1);
}

__global__ __launch_bounds__(256)
void scan_kernel(const int* __restrict__ deg, int* __restrict__ row_ptr, int N)
{
    __shared__ int sums[256];
    __shared__ int offs[257];
    const int t = threadIdx.x;
    const int chunk = (N + 255) / 256;
    int b = t * chunk, e = min(N, b + chunk);
    int s = 0;
    for (int k = b; k < e; k++) s += deg[k];
    sums[t] = s;
    __syncthreads();
    if (t == 0) {
        int run = 0;
        for (int i = 0; i < 256; i++) { offs[i] = run; run += sums[i]; }
        offs[256] = run;
    }
    __syncthreads();
    int run = offs[t];
    for (int k = b; k < e; k++) { row_ptr[k] = run; run += deg[k]; }
    if (t == 255) row_ptr[N] = offs[256];
}

__global__ void fill_kernel(const int* __restrict__ rcv, const int* __restrict__ row_ptr,
                            int* __restrict__ cursor, int* __restrict__ eidx, int E)
{
    int e = blockIdx.x * 256 + threadIdx.x;
    if (e < E) {
        int r = rcv[e];
        int pos = atomicAdd(&cursor[r], 1);
        eidx[row_ptr[r] + pos] = e;
    }
}

// ---------------- self linear: wave-per-node, 4 nodes/block ----------------
__global__ __launch_bounds__(256)
void self_kernel(const float* __restrict__ fs, const float* __restrict__ fv,
                 const float* __restrict__ Wes, const float* __restrict__ Wev,
                 float* __restrict__ out, int N)
{
    __shared__ float s_l[4][NC];
    __shared__ float v_l[4][3][NC];
    const int t = threadIdx.x, wv = t >> 6, lane = t & 63;
    const int n = blockIdx.x * 4 + wv;

    if (n < N) {
        s_l[wv][lane] = fs[(size_t)n * NC + lane];
        v_l[wv][0][lane] = fv[(size_t)n * NC * 3 + lane * 3 + 0];
        v_l[wv][1][lane] = fv[(size_t)n * NC * 3 + lane * 3 + 1];
        v_l[wv][2][lane] = fv[(size_t)n * NC * 3 + lane * 3 + 2];
    }
    __syncthreads();
    if (n >= N) return;

    const int d = lane;
    float a = 0.f, bx = 0.f, by = 0.f, bz = 0.f;
    #pragma unroll 8
    for (int c = 0; c < NC; c++) {
        float ws = Wes[c * NC + d];
        float wvv = Wev[c * NC + d];
        a  += s_l[wv][c] * ws;
        bx += v_l[wv][0][c] * wvv;
        by += v_l[wv][1][c] * wvv;
        bz += v_l[wv][2][c] * wvv;
    }
    out[(size_t)N * 256 + (size_t)n * NC + d]            = a  * 0.125f;
    out[(size_t)N * 320 + (size_t)n * 192 +       d]     = bx * 0.125f;
    out[(size_t)N * 320 + (size_t)n * 192 +  64 + d]     = by * 0.125f;
    out[(size_t)N * 320 + (size_t)n * 192 + 128 + d]     = bz * 0.125f;
}

// ---------------------------------------------------------------------------
// Edge kernel: 128 CSR positions per 128-thread block. (structure = r7,
// which measured 364 us; only change: sh0+sh1 packed into one float4 row ->
// one ds_read_b128 per edge per pass instead of 4 scalar LDS reads)
// ---------------------------------------------------------------------------
__global__ __launch_bounds__(128, 3)
void edge_kernel(const float* __restrict__ ef, const float* __restrict__ sh0,
                 const float* __restrict__ sh1,
                 const int* __restrict__ snd, const int* __restrict__ rcv,
                 const float* __restrict__ W1, const float* __restrict__ W2,
                 const float* __restrict__ W3, const float* __restrict__ W4,
                 const float* __restrict__ s_st, const float* __restrict__ v_st,
                 const int* __restrict__ eidx,
                 float* __restrict__ m, int E)
{
    __shared__ unsigned int h_l[TEB][36];   // 32 packed f16x2 + pad (144B rows)
    __shared__ float sh_l[TEB][4];          // {sh0, sh1x, sh1y, sh1z}
    __shared__ int   snd_l[TEB];
    __shared__ int   rcv_l[TEB];

    const int t = threadIdx.x;
    const int p0 = blockIdx.x * TEB;

    // ---------------- phase 1 ----------------
    {
        int p = p0 + t;
        bool valid = p < E;
        int e = valid ? eidx[p] : 0;
        snd_l[t] = valid ? snd[e] : 0;
        rcv_l[t] = valid ? rcv[e] : -1;
        sh_l[t][0] = valid ? sh0[e] : 0.f;
        sh_l[t][1] = valid ? sh1[(size_t)e * 3 + 0] : 0.f;
        sh_l[t][2] = valid ? sh1[(size_t)e * 3 + 1] : 0.f;
        sh_l[t][3] = valid ? sh1[(size_t)e * 3 + 2] : 0.f;

        float x[NRAD];
        #pragma unroll
        for (int r = 0; r < NRAD; r++)
            x[r] = valid ? ef[(size_t)e * NRAD + r] : 0.f;

        // layer 1: 8 -> 64 (h1 in registers)
        float h1[NH];
        #pragma unroll
        for (int j = 0; j < NH; j++) {
            float a = 0.f;
            #pragma unroll
            for (int r = 0; r < NRAD; r++) a += x[r] * W1[r * NH + j];
            h1[j] = silu_f(a * 0.35355339059327373f);   // 1/sqrt(8)
        }

        // layer 2: h1(f32 regs) -> h2 packed f16 (32 uint regs)
        unsigned int h2p[32];
        for (int jt = 0; jt < 16; jt++) {
            float a0 = 0.f, a1 = 0.f, a2 = 0.f, a3 = 0.f;
            #pragma unroll
            for (int c = 0; c < NH; c++) {
                float hv = h1[c];
                const float* wr = W2 + c * NH + jt * 4;
                a0 += hv * wr[0]; a1 += hv * wr[1];
                a2 += hv * wr[2]; a3 += hv * wr[3];
            }
            h2p[jt * 2 + 0] = pkh(silu_f(a0 * 0.125f), silu_f(a1 * 0.125f));
            h2p[jt * 2 + 1] = pkh(silu_f(a2 * 0.125f), silu_f(a3 * 0.125f));
        }
        // layer 3: h2 packed -> h3 packed -> LDS (h1 dead; regs reused)
        for (int jt = 0; jt < 16; jt++) {
            float a0 = 0.f, a1 = 0.f, a2 = 0.f, a3 = 0.f;
            #pragma unroll
            for (int cp = 0; cp < 32; cp++) {
                h2v u = uph(h2p[cp]);
                float hl = (float)u[0], hh = (float)u[1];
                const float* wr0 = W3 + (2 * cp) * NH + jt * 4;
                const float* wr1 = W3 + (2 * cp + 1) * NH + jt * 4;
                a0 += hl * wr0[0] + hh * wr1[0];
                a1 += hl * wr0[1] + hh * wr1[1];
                a2 += hl * wr0[2] + hh * wr1[2];
                a3 += hl * wr0[3] + hh * wr1[3];
            }
            h_l[t][jt * 2 + 0] = pkh(silu_f(a0 * 0.125f), silu_f(a1 * 0.125f));
            h_l[t][jt * 2 + 1] = pkh(silu_f(a2 * 0.125f), silu_f(a3 * 0.125f));
        }
    }
    __syncthreads();

    // ---------------- phase 2 ----------------
    const int wv = t >> 6, lane = t & 63;
    const int base = wv * 64;
    const int v_sd = snd_l[base + lane];   // sender of edge i in lane i
    const int v_rc = rcv_l[base + lane];   // receiver of edge i in lane i

    // ---- pass A: slices {0,2} -> p1,p3; one se gather per edge ------------
    {
        unsigned int WA[32], WC[32];
        #pragma unroll
        for (int q = 0; q < 32; q++) {
            WA[q] = pkh(W4[(2 * q) * 320 + lane],       W4[(2 * q + 1) * 320 + lane]);
            WC[q] = pkh(W4[(2 * q) * 320 + 128 + lane], W4[(2 * q + 1) * 320 + 128 + lane]);
        }
        #pragma unroll
        for (int q = 0; q < 32; q++) {
            asm volatile("" : "+v"(WA[q]));
            asm volatile("" : "+v"(WC[q]));
        }
        float g0 = s_st[(size_t)__builtin_amdgcn_readlane(v_sd, 0) * NC + lane];
        float g1 = s_st[(size_t)__builtin_amdgcn_readlane(v_sd, 1) * NC + lane];
        float g2 = s_st[(size_t)__builtin_amdgcn_readlane(v_sd, 2) * NC + lane];
        float g3 = s_st[(size_t)__builtin_amdgcn_readlane(v_sd, 3) * NC + lane];
        int r_cur = -1;
        float a1 = 0.f, a3x = 0.f, a3y = 0.f, a3z = 0.f;
        #pragma unroll 4
        for (int ei = 0; ei < 64; ei++) {
            const int pn = (ei + 4 > 63) ? 63 : ei + 4;
            const float gf = s_st[(size_t)__builtin_amdgcn_readlane(v_sd, pn) * NC + lane];
            const int r = __builtin_amdgcn_readlane(v_rc, ei);
            if (r != r_cur) {
                if (r_cur >= 0) {
                    float* mb = m + (size_t)r_cur * MPN;
                    unsafeAtomicAdd(mb + lane,             a1);
                    unsafeAtomicAdd(mb + 128 + lane,       a3x);
                    unsafeAtomicAdd(mb + 128 + 192 + lane, a3y);
                    unsafeAtomicAdd(mb + 128 + 384 + lane, a3z);
                    a1 = a3x = a3y = a3z = 0.f;
                }
                r_cur = r;
            }
            if (r >= 0) {
                const int pos = base + ei;
                float w1w, w3w;
                dot2w((const uint4*)(&h_l[pos][0]), WA, WC, w1w, w3w);
                float4 sh4 = *(const float4*)(&sh_l[pos][0]);
                float se = g0;
                a1 += w1w * se * sh4.x;
                float t3 = w3w * se;
                a3x += t3 * sh4.y;
                a3y += t3 * sh4.z;
                a3z += t3 * sh4.w;
            }
            g0 = g1; g1 = g2; g2 = g3; g3 = gf;
        }
        if (r_cur >= 0) {
            float* mb = m + (size_t)r_cur * MPN;
            unsafeAtomicAdd(mb + lane,             a1);
            unsafeAtomicAdd(mb + 128 + lane,       a3x);
            unsafeAtomicAdd(mb + 128 + 192 + lane, a3y);
            unsafeAtomicAdd(mb + 128 + 384 + lane, a3z);
        }
    }

    // ---- pass B: slices {1,3,4} -> p2,p4,p5; one v gather per edge --------
    {
        unsigned int WB[32], WD[32], WE[32];
        #pragma unroll
        for (int q = 0; q < 32; q++) {
            WB[q] = pkh(W4[(2 * q) * 320 +  64 + lane], W4[(2 * q + 1) * 320 +  64 + lane]);
            WD[q] = pkh(W4[(2 * q) * 320 + 192 + lane], W4[(2 * q + 1) * 320 + 192 + lane]);
            WE[q] = pkh(W4[(2 * q) * 320 + 256 + lane], W4[(2 * q + 1) * 320 + 256 + lane]);
        }
        #pragma unroll
        for (int q = 0; q < 32; q++) {
            asm volatile("" : "+v"(WB[q]));
            asm volatile("" : "+v"(WD[q]));
            asm volatile("" : "+v"(WE[q]));
        }
        float gx0, gy0, gz0, gx1, gy1, gz1, gx2, gy2, gz2, gx3, gy3, gz3;
        {
            size_t s0 = (size_t)__builtin_amdgcn_readlane(v_sd, 0) * 192;
            size_t s1 = (size_t)__builtin_amdgcn_readlane(v_sd, 1) * 192;
            size_t s2 = (size_t)__builtin_amdgcn_readlane(v_sd, 2) * 192;
            size_t s3 = (size_t)__builtin_amdgcn_readlane(v_sd, 3) * 192;
            gx0 = v_st[s0 + lane]; gy0 = v_st[s0 + 64 + lane]; gz0 = v_st[s0 + 128 + lane];
            gx1 = v_st[s1 + lane]; gy1 = v_st[s1 + 64 + lane]; gz1 = v_st[s1 + 128 + lane];
            gx2 = v_st[s2 + lane]; gy2 = v_st[s2 + 64 + lane]; gz2 = v_st[s2 + 128 + lane];
            gx3 = v_st[s3 + lane]; gy3 = v_st[s3 + 64 + lane]; gz3 = v_st[s3 + 128 + lane];
        }
        int r_cur = -1;
        float a2 = 0.f;
        float a4x = 0.f, a4y = 0.f, a4z = 0.f;
        float a5x = 0.f, a5y = 0.f, a5z = 0.f;
        #pragma unroll 4
        for (int ei = 0; ei < 64; ei++) {
            const int pn = (ei + 4 > 63) ? 63 : ei + 4;
            size_t sb = (size_t)__builtin_amdgcn_readlane(v_sd, pn) * 192;
            const float gxf = v_st[sb + lane];
            const float gyf = v_st[sb + 64 + lane];
            const float gzf = v_st[sb + 128 + lane];
            const int r = __builtin_amdgcn_readlane(v_rc, ei);
            if (r != r_cur) {
                if (r_cur >= 0) {
                    float* mb = m + (size_t)r_cur * MPN;
                    unsafeAtomicAdd(mb + 64 + lane,              a2);
                    unsafeAtomicAdd(mb + 128 + 64 + lane,        a4x);
                    unsafeAtomicAdd(mb + 128 + 192 + 64 + lane,  a4y);
                    unsafeAtomicAdd(mb + 128 + 384 + 64 + lane,  a4z);
                    unsafeAtomicAdd(mb + 128 + 128 + lane,       a5x);
                    unsafeAtomicAdd(mb + 128 + 192 + 128 + lane, a5y);
                    unsafeAtomicAdd(mb + 128 + 384 + 128 + lane, a5z);
                    a2 = a4x = a4y = a4z = a5x = a5y = a5z = 0.f;
                }
                r_cur = r;
            }
            if (r >= 0) {
                const int pos = base + ei;
                float w2w, w4w, w5w;
                dot3w((const uint4*)(&h_l[pos][0]), WB, WD, WE, w2w, w4w, w5w);
                float4 sh4 = *(const float4*)(&sh_l[pos][0]);
                float vx = gx0, vy = gy0, vz = gz0;
                float dot = vx * sh4.y + vy * sh4.z + vz * sh4.w;
                a2 += w2w * dot * 0.5773502691896258f;   // 1/sqrt(3)
                float w4s = w4w * sh4.x;
                a4x += w4s * vx; a4y += w4s * vy; a4z += w4s * vz;
                float w5s = w5w * 0.7071067811865476f;   // 1/sqrt(2)
                a5x += w5s * (vy * sh4.w - vz * sh4.z);
                a5y += w5s * (vz * sh4.y - vx * sh4.w);
                a5z += w5s * (vx * sh4.z - vy * sh4.y);
            }
            gx0 = gx1; gy0 = gy1; gz0 = gz1;
            gx1 = gx2; gy1 = gy2; gz1 = gz2;
            gx2 = gx3; gy2 = gy3; gz2 = gz3;
            gx3 = gxf; gy3 = gyf; gz3 = gzf;
        }
        if (r_cur >= 0) {
            float* mb = m + (size_t)r_cur * MPN;
            unsafeAtomicAdd(mb + 64 + lane,              a2);
            unsafeAtomicAdd(mb + 128 + 64 + lane,        a4x);
            unsafeAtomicAdd(mb + 128 + 192 + 64 + lane,  a4y);
            unsafeAtomicAdd(mb + 128 + 384 + 64 + lane,  a4z);
            unsafeAtomicAdd(mb + 128 + 128 + lane,       a5x);
            unsafeAtomicAdd(mb + 128 + 192 + 128 + lane, a5y);
            unsafeAtomicAdd(mb + 128 + 384 + 128 + lane, a5z);
        }
    }
}

// ---------------------------------------------------------------------------
// Fused post-GEMM kernel: blockIdx.y = 0..3 -> skip-connection parts
// (A = feat*attr on the fly, K=640), 4..7 -> output-linear parts over m
// (K=128/192). 256n x 64d tile, 256 threads, 16n x 4d per thread (4 n-sub-
// blocks): 5 LDS b128 reads per 64 fd2 (was 2 per 16) -- cuts the LDS-
// throughput bottleneck ~1.6x. All LDS reads 2-way-conflict-free/broadcast.
// f16x2 packed tiles, f32 accumulation.
// ---------------------------------------------------------------------------
__global__ __launch_bounds__(256)
void post_kernel(const float* __restrict__ attrs, const float* __restrict__ fs,
                 const float* __restrict__ fv,
                 const float* __restrict__ Wss, const float* __restrict__ Wsv,
                 const float* __restrict__ m,
                 const float* __restrict__ Wos, const float* __restrict__ Wov,
                 float* __restrict__ out, int N)
{
    __shared__ unsigned int At[32][260];   // [k-pair][n 0..255 + pad]
    __shared__ unsigned int Bt[32][68];    // [k-pair][d + pad]

    const int y = blockIdx.y;
    const bool is_sc = (y < 4);
    const int part = is_sc ? y : y - 4;
    const int n0 = blockIdx.x * 256;
    const int t = threadIdx.x;
    const int tn = t & 15, td = t >> 4;
    const int x = part - 1;

    const float* W;
    int nkt, aoff = 0;
    if (is_sc) { W = (part == 0) ? Wss : Wsv; nkt = 10; }
    else {
        W = (part == 0) ? Wos : Wov;
        nkt = (part == 0) ? 2 : 3;
        aoff = (part == 0) ? 0 : 128 + x * 192;
    }

    float acc[16][4];
    #pragma unroll
    for (int i = 0; i < 16; i++)
        #pragma unroll
        for (int j = 0; j < 4; j++) acc[i][j] = 0.f;

    for (int kt = 0; kt < nkt; kt++) {
        __syncthreads();
        if (is_sc) {
            // A = (feat * attr) built on the fly, packed k-pairs
            for (int i = t; i < 8192; i += 256) {
                int n = i >> 5, kp = i & 31;
                int k0 = kt * 64 + kp * 2;
                int c0 = k0 / 10, am0 = k0 - c0 * 10;
                int k1 = k0 + 1;
                int c1 = k1 / 10, am1 = k1 - c1 * 10;
                int ng = n0 + n;
                float f0 = 0.f, f1 = 0.f;
                if (ng < N) {
                    float fa = (part == 0) ? fs[(size_t)ng * 64 + c0]
                                           : fv[((size_t)ng * 64 + c0) * 3 + x];
                    float fb = (part == 0) ? fs[(size_t)ng * 64 + c1]
                                           : fv[((size_t)ng * 64 + c1) * 3 + x];
                    f0 = fa * attrs[(size_t)ng * 10 + am0];
                    f1 = fb * attrs[(size_t)ng * 10 + am1];
                }
                At[kp][n] = pkh(f0, f1);
            }
        } else {
            for (int i = t; i < 8192; i += 256) {
                int n = i >> 5, kp = i & 31;
                int ng = n0 + n;
                float f0 = 0.f, f1 = 0.f;
                if (ng < N) {
                    const float* mp = m + (size_t)ng * MPN + aoff + kt * 64 + kp * 2;
                    f0 = mp[0]; f1 = mp[1];
                }
                At[kp][n] = pkh(f0, f1);
            }
        }
        // B tile (coalesced in d)
        for (int i = t; i < 2048; i += 256) {
            int kp = i >> 6, d = i & 63;
            Bt[kp][d] = pkh(W[(size_t)(kt * 64 + 2 * kp) * 64 + d],
                            W[(size_t)(kt * 64 + 2 * kp + 1) * 64 + d]);
        }
        __syncthreads();
        #pragma unroll 4
        for (int kp = 0; kp < 32; kp++) {
            uint4 bu = *(const uint4*)(&Bt[kp][td * 4]);
            unsigned int bb[4] = {bu.x, bu.y, bu.z, bu.w};
            #pragma unroll
            for (int sb = 0; sb < 4; sb++) {
                uint4 au = *(const uint4*)(&At[kp][sb * 64 + tn * 4]);
                unsigned int aa[4] = {au.x, au.y, au.z, au.w};
                #pragma unroll
                for (int i = 0; i < 4; i++)
                    #pragma unroll
                    for (int j = 0; j < 4; j++)
                        acc[sb * 4 + i][j] = fd2(aa[i], bb[j], acc[sb * 4 + i][j]);
            }
        }
    }

    float scale;
    if (is_sc) scale = 0.03952847075210474f;                   // 1/sqrt(640)
    else scale = (part == 0) ? 0.005524271728019903f           // 1/(sqrt(128)*16)
                             : 0.004510527174164819f;          // 1/(sqrt(192)*16)

    #pragma unroll
    for (int sb = 0; sb < 4; sb++) {
        #pragma unroll
        for (int i = 0; i < 4; i++) {
            int ng = n0 + sb * 64 + tn * 4 + i;
            if (ng >= N) continue;
            #pragma unroll
            for (int j = 0; j < 4; j++) {
                int d = td * 4 + j;
                float v = acc[sb * 4 + i][j] * scale;
                if (is_sc) {
                    if (part == 0) out[(size_t)N * 256 + (size_t)ng * 64 + d] = v;
                    else           out[(size_t)N * 320 + (size_t)ng * 192 + d * 3 + x] = v;
                } else {
                    if (part == 0) out[(size_t)ng * 64 + d] = v;
                    else           out[(size_t)N * 64 + (size_t)ng * 192 + d * 3 + x] = v;
                }
            }
        }
    }
}

// ---------------------------------------------------------------------------
extern "C" void kernel_launch(void* const* d_in, const int* in_sizes, int n_in,
                              void* d_out, int out_size, void* d_ws, size_t ws_size,
                              hipStream_t stream)
{
    const float* attrs = (const float*)d_in[0];
    const float* fs    = (const float*)d_in[1];
    const float* fv    = (const float*)d_in[2];
    const float* sh0   = (const float*)d_in[3];
    const float* sh1   = (const float*)d_in[4];
    const float* ef    = (const float*)d_in[5];
    const int*   snd   = (const int*)d_in[6];
    const int*   rcv   = (const int*)d_in[7];
    const float* Wss   = (const float*)d_in[8];
    const float* Wsv   = (const float*)d_in[9];
    const float* Wes   = (const float*)d_in[10];
    const float* Wev   = (const float*)d_in[11];
    const float* W1    = (const float*)d_in[12];
    const float* W2    = (const float*)d_in[13];
    const float* W3    = (const float*)d_in[14];
    const float* W4    = (const float*)d_in[15];
    const float* Wos   = (const float*)d_in[16];
    const float* Wov   = (const float*)d_in[17];

    const int N = in_sizes[0] / NATTR;   // 50000
    const int E = in_sizes[6];           // 320000

    float* out = (float*)d_out;
    const float* s_st = out + (size_t)N * 256;  // self-linear s scratch
    const float* v_st = out + (size_t)N * 320;  // self-linear v scratch

    // CSR int scratch in d_out's out region (overwritten later by post)
    int* deg     = (int*)d_out;
    int* cursor  = deg + N;
    int* row_ptr = cursor + N;
    int* eidx    = row_ptr + N + 1;

    float* m = (float*)d_ws;             // N*704 f32 = 140.8 MB

    (void)hipMemsetAsync(deg, 0, (size_t)2 * N * sizeof(int), stream);
    (void)hipMemsetAsync(m, 0, (size_t)N * MPN * sizeof(float), stream);

    const int eb = (E + 255) / 256;
    hist_kernel<<<eb, 256, 0, stream>>>(rcv, deg, E);
    scan_kernel<<<1, 256, 0, stream>>>(deg, row_ptr, N);
    fill_kernel<<<eb, 256, 0, stream>>>(rcv, row_ptr, cursor, eidx, E);

    self_kernel<<<(N + 3) / 4, 256, 0, stream>>>(fs, fv, Wes, Wev, out, N);

    const int nbe = (E + TEB - 1) / TEB;
    edge_kernel<<<nbe, 128, 0, stream>>>(ef, sh0, sh1, snd, rcv,
                                         W1, W2, W3, W4, s_st, v_st,
                                         eidx, m, E);

    dim3 g_post((N + 255) / 256, 8);
    post_kernel<<<g_post, 256, 0, stream>>>(attrs, fs, fv, Wss, Wsv,
                                            m, Wos, Wov, out, N);
}